// Round 6
// baseline (208.121 us; speedup 1.0000x reference)
//
#include <hip/hip_runtime.h>
#include <math.h>

// Problem constants
#define B_   8
#define C_   64
#define O_   64
#define H_   128
#define W_   128
#define HW_  (H_ * W_)
#define KSZ  576            // C_*9 contraction length

typedef _Float16 f16x8 __attribute__((ext_vector_type(8)));
typedef _Float16 f16x2 __attribute__((ext_vector_type(2)));
typedef float    f32x4 __attribute__((ext_vector_type(4)));

#define WPM_BYTES (18 * 4 * 64 * 8 * 2)   // 73728
#define WPA_BYTES (18 * 2 * 64 * 8 * 2)   // 36864
#define XB_       ((B_ * HW_ * 8) / 256)  // 4096 transpose blocks

// ---------------------------------------------------------------------------
// Prep kernel: blocks [0,XB_) transpose x (B,C,H,W) fp32 -> (B,H,W,C) f16;
// blocks [XB_, XB_+27) prepack weights into f16 MFMA A-fragment layout.
// A-frag element (chunk s, m-tile mt, lane, j):
//   row = mt*16+(lane&15), k-local = (lane>>4)*8+j; tap k=s>>1, cbase=(s&1)*32.
// ---------------------------------------------------------------------------
__global__ __launch_bounds__(256) void prep_kernel(
    const float* __restrict__ x,
    const float* __restrict__ offw, const float* __restrict__ modw,
    const float* __restrict__ wgt,
    _Float16* __restrict__ xT, _Float16* __restrict__ wpM, _Float16* __restrict__ wpA)
{
    const int bi = blockIdx.x;
    if (bi < XB_) {
        const int t  = bi * 256 + threadIdx.x;  // (pixel<<3) | cg
        const int p  = t >> 3;
        const int cg = t & 7;
        const int b  = p >> 14;
        const int pp = p & 16383;
        const float* __restrict__ xp = x + (size_t)b * C_ * HW_ + (size_t)(cg * 8) * HW_ + pp;
        f16x8 v;
#pragma unroll
        for (int j = 0; j < 8; ++j) v[j] = (_Float16)xp[(size_t)j * HW_];
        *(f16x8*)&xT[(size_t)t * 8] = v;
        return;
    }
    const int g = (bi - XB_) * 256 + threadIdx.x;
    if (g < 18 * 4 * 64) {
        const int s = g >> 8, mt = (g >> 6) & 3, lane = g & 63;
        const int k = s >> 1, cb = (s & 1) * 32;
        const int o  = mt * 16 + (lane & 15);
        const int c0 = cb + (lane >> 4) * 8;
        f16x8 v;
#pragma unroll
        for (int j = 0; j < 8; ++j) v[j] = (_Float16)wgt[o * KSZ + (c0 + j) * 9 + k];
        *(f16x8*)&wpM[(size_t)g * 8] = v;
    } else if (g < 18 * 4 * 64 + 18 * 2 * 64) {
        const int u = g - 18 * 4 * 64;
        const int s = u >> 7, mt = (u >> 6) & 1, lane = u & 63;
        const int k = s >> 1, cb = (s & 1) * 32;
        const int t  = mt * 16 + (lane & 15);
        const int c0 = cb + (lane >> 4) * 8;
        f16x8 v;
#pragma unroll
        for (int j = 0; j < 8; ++j) {
            float w = 0.0f;
            if (t < 18)      w = offw[t * KSZ + (c0 + j) * 9 + k];
            else if (t < 27) w = modw[(t - 18) * KSZ + (c0 + j) * 9 + k];
            v[j] = (_Float16)w;
        }
        *(f16x8*)&wpA[(size_t)u * 8] = v;
    }
}

// ---------------------------------------------------------------------------
// Fused main kernel. Block = 256 thr (4 waves) owns a full 128-px row; each
// wave owns 32 px (2 N-tiles). Barrier-free K-loops; the f16 bilinear combine
// (v_pk_fma_f16) produces the MFMA B-fragment in place (n=ln, k=lq*8+j).
// ---------------------------------------------------------------------------
__global__ __launch_bounds__(256, 4) void dcn_main_kernel(
    const _Float16* __restrict__ xT,    // (B, H, W, C) f16
    const _Float16* __restrict__ wpA,   // packed offset/mod weight frags
    const _Float16* __restrict__ wpM,   // packed main weight frags
    const float* __restrict__ offb,     // (18,)
    const float* __restrict__ modb,     // (9,)
    float* __restrict__ out)            // (B, O, H, W)
{
    __shared__ float params[4][27][32];   // [wave][t][px-in-wave-tile]

    const int tid  = threadIdx.x;
    const int lane = tid & 63;
    const int wave = tid >> 6;
    const int lq   = lane >> 4;
    const int ln   = lane & 15;

    const int bi = blockIdx.x;
    const int b  = bi & 7;               // XCD-pinned batch
    const int ho = bi >> 3;

    const _Float16* __restrict__ xbT = xT + (size_t)b * HW_ * 64;

    // ---------------- Phase A: offset/modulator conv via MFMA ----------------
    f32x4 accA[2][2];
#pragma unroll
    for (int mt = 0; mt < 2; ++mt)
#pragma unroll
        for (int nt = 0; nt < 2; ++nt)
            accA[mt][nt] = (f32x4){0.f, 0.f, 0.f, 0.f};

#pragma unroll
    for (int s = 0; s < 18; ++s) {
        const int k = s >> 1, cb = (s & 1) * 32;
        const int ki = k / 3, kj = k - ki * 3;
        const int y  = ho - 1 + ki;
        const bool vy = (y >= 0) && (y < H_);
        f16x8 afA[2];
#pragma unroll
        for (int mt = 0; mt < 2; ++mt)
            afA[mt] = *(const f16x8*)&wpA[(size_t)((s * 2 + mt) * 64 + lane) * 8];
        f16x8 bfA[2];
#pragma unroll
        for (int nt = 0; nt < 2; ++nt) {
            const int wo = wave * 32 + nt * 16 + ln;
            const int xx = wo - 1 + kj;
            const bool v = vy && (xx >= 0) && (xx < W_);
            if (v) {
                bfA[nt] = *(const f16x8*)&xbT[((size_t)(y * W_ + xx)) * 64 + cb + lq * 8];
            } else {
#pragma unroll
                for (int j = 0; j < 8; ++j) bfA[nt][j] = (_Float16)0.0f;
            }
        }
#pragma unroll
        for (int mt = 0; mt < 2; ++mt)
#pragma unroll
            for (int nt = 0; nt < 2; ++nt)
                accA[mt][nt] = __builtin_amdgcn_mfma_f32_16x16x32_f16(afA[mt], bfA[nt], accA[mt][nt], 0, 0, 0);
    }

    // Epilogue A: D col = ln (px in 16-tile), row = mt*16 + lq*4 + r = param t.
#pragma unroll
    for (int mt = 0; mt < 2; ++mt)
#pragma unroll
        for (int nt = 0; nt < 2; ++nt)
#pragma unroll
            for (int r = 0; r < 4; ++r) {
                const int t = mt * 16 + lq * 4 + r;
                const float val = accA[mt][nt][r];
                if (t < 18)      params[wave][t][nt * 16 + ln] = val + offb[t];
                else if (t < 27) params[wave][t][nt * 16 + ln] = 2.0f / (1.0f + expf(-(val + modb[t - 18])));
            }
    __syncthreads();

    // ---------------- Phase B: deformable gather + MFMA ----------------
    f32x4 acc[4][2];
#pragma unroll
    for (int mt = 0; mt < 4; ++mt)
#pragma unroll
        for (int nt = 0; nt < 2; ++nt)
            acc[mt][nt] = (f32x4){0.f, 0.f, 0.f, 0.f};

#pragma unroll
    for (int s = 0; s < 18; ++s) {
        const int k = s >> 1, cb = (s & 1) * 32;
        const int ki = k / 3, kj = k - ki * 3;

        f16x8 af[4];
#pragma unroll
        for (int mt = 0; mt < 4; ++mt)
            af[mt] = *(const f16x8*)&wpM[(size_t)((s * 4 + mt) * 64 + lane) * 8];

        f16x8 bf[2];
#pragma unroll
        for (int nt = 0; nt < 2; ++nt) {
            const int pxw = nt * 16 + ln;
            const int wo  = wave * 32 + pxw;
            const float dy = params[wave][2 * k][pxw];
            const float dx = params[wave][2 * k + 1][pxw];
            const float mk = params[wave][18 + k][pxw];

            const float ys = (float)(ho - 1 + ki) + dy;
            const float xs = (float)(wo - 1 + kj) + dx;
            const float y0f = floorf(ys), x0f = floorf(xs);
            const float wy = ys - y0f, wx = xs - x0f;
            const int y0 = (int)y0f, x0 = (int)x0f;
            const int y1 = y0 + 1,  x1 = x0 + 1;
            const bool vy0 = (y0 >= 0) && (y0 < H_);
            const bool vy1 = (y1 >= 0) && (y1 < H_);
            const bool vx0 = (x0 >= 0) && (x0 < W_);
            const bool vx1 = (x1 >= 0) && (x1 < W_);
            const int yc0 = min(max(y0, 0), H_ - 1);
            const int yc1 = min(max(y1, 0), H_ - 1);
            const int xc0 = min(max(x0, 0), W_ - 1);
            const int xc1 = min(max(x1, 0), W_ - 1);
            float w00 = (1.0f - wy) * (1.0f - wx) * mk; if (!(vy0 && vx0)) w00 = 0.0f;
            float w01 = (1.0f - wy) * wx          * mk; if (!(vy0 && vx1)) w01 = 0.0f;
            float w10 = wy          * (1.0f - wx) * mk; if (!(vy1 && vx0)) w10 = 0.0f;
            float w11 = wy          * wx          * mk; if (!(vy1 && vx1)) w11 = 0.0f;

            const int c0 = cb + lq * 8;
            union U { f16x8 v; f16x2 p[4]; };
            U a00, a01, a10, a11, r;
            a00.v = *(const f16x8*)&xbT[((size_t)(yc0 * W_ + xc0)) * 64 + c0];
            a01.v = *(const f16x8*)&xbT[((size_t)(yc0 * W_ + xc1)) * 64 + c0];
            a10.v = *(const f16x8*)&xbT[((size_t)(yc1 * W_ + xc0)) * 64 + c0];
            a11.v = *(const f16x8*)&xbT[((size_t)(yc1 * W_ + xc1)) * 64 + c0];

            const _Float16 h00 = (_Float16)w00, h01 = (_Float16)w01;
            const _Float16 h10 = (_Float16)w10, h11 = (_Float16)w11;
            const f16x2 w00h = {h00, h00}, w01h = {h01, h01};
            const f16x2 w10h = {h10, h10}, w11h = {h11, h11};
#pragma unroll
            for (int u = 0; u < 4; ++u)
                r.p[u] = a00.p[u] * w00h + a01.p[u] * w01h
                       + a10.p[u] * w10h + a11.p[u] * w11h;   // v_pk_fma_f16 chain
            bf[nt] = r.v;
        }
#pragma unroll
        for (int mt = 0; mt < 4; ++mt)
#pragma unroll
            for (int nt = 0; nt < 2; ++nt)
                acc[mt][nt] = __builtin_amdgcn_mfma_f32_16x16x32_f16(af[mt], bf[nt], acc[mt][nt], 0, 0, 0);
    }

    // Epilogue B: D col = ln -> px, row = o.
    float* __restrict__ ob = out + (size_t)b * O_ * HW_ + (size_t)ho * W_;
#pragma unroll
    for (int mt = 0; mt < 4; ++mt)
#pragma unroll
        for (int nt = 0; nt < 2; ++nt) {
            const int wo = wave * 32 + nt * 16 + ln;
#pragma unroll
            for (int r = 0; r < 4; ++r) {
                const int o = mt * 16 + lq * 4 + r;
                ob[(size_t)o * HW_ + wo] = acc[mt][nt][r];
            }
        }
}

extern "C" void kernel_launch(void* const* d_in, const int* in_sizes, int n_in,
                              void* d_out, int out_size, void* d_ws, size_t ws_size,
                              hipStream_t stream) {
    (void)in_sizes; (void)n_in; (void)out_size; (void)ws_size;
    const float* x    = (const float*)d_in[0];
    const float* offw = (const float*)d_in[1];
    const float* offb = (const float*)d_in[2];
    const float* modw = (const float*)d_in[3];
    const float* modb = (const float*)d_in[4];
    const float* wgt  = (const float*)d_in[5];
    float* out = (float*)d_out;

    _Float16* wpM = (_Float16*)d_ws;                                   // 73728 B
    _Float16* wpA = (_Float16*)((char*)d_ws + WPM_BYTES);              // 36864 B
    _Float16* xT  = (_Float16*)((char*)d_ws + WPM_BYTES + WPA_BYTES);  // 16.78 MB

    prep_kernel<<<XB_ + 27, 256, 0, stream>>>(x, offw, modw, wgt, xT, wpM, wpA);
    dcn_main_kernel<<<B_ * H_, 256, 0, stream>>>(xT, wpA, wpM, offb, modb, out);
}

// Round 7
// 206.284 us; speedup vs baseline: 1.0089x; 1.0089x over previous
//
#include <hip/hip_runtime.h>
#include <math.h>

// Problem constants
#define B_   8
#define C_   64
#define O_   64
#define H_   128
#define W_   128
#define HW_  (H_ * W_)
#define KSZ  576            // C_*9 contraction length

typedef _Float16 f16x8 __attribute__((ext_vector_type(8)));
typedef float    f32x4 __attribute__((ext_vector_type(4)));

#define WPM_BYTES (18 * 4 * 64 * 8 * 2)   // 73728
#define WPA_BYTES (18 * 2 * 64 * 8 * 2)   // 36864
#define XB_       ((B_ * HW_ * 8) / 256)  // 4096 transpose blocks

// ---------------------------------------------------------------------------
// Prep kernel: blocks [0,XB_) transpose x (B,C,H,W) fp32 -> (B,H,W,C) f16;
// blocks [XB_, XB_+27) prepack weights into f16 MFMA A-fragment layout.
// A-frag element (chunk s, m-tile mt, lane, j):
//   row = mt*16+(lane&15), k-local = (lane>>4)*8+j; tap k=s>>1, cbase=(s&1)*32.
// ---------------------------------------------------------------------------
__global__ __launch_bounds__(256) void prep_kernel(
    const float* __restrict__ x,
    const float* __restrict__ offw, const float* __restrict__ modw,
    const float* __restrict__ wgt,
    _Float16* __restrict__ xT, _Float16* __restrict__ wpM, _Float16* __restrict__ wpA)
{
    const int bi = blockIdx.x;
    if (bi < XB_) {
        const int t  = bi * 256 + threadIdx.x;  // (pixel<<3) | cg
        const int p  = t >> 3;
        const int cg = t & 7;
        const int b  = p >> 14;
        const int pp = p & 16383;
        const float* __restrict__ xp = x + (size_t)b * C_ * HW_ + (size_t)(cg * 8) * HW_ + pp;
        f16x8 v;
#pragma unroll
        for (int j = 0; j < 8; ++j) v[j] = (_Float16)xp[(size_t)j * HW_];
        *(f16x8*)&xT[(size_t)t * 8] = v;
        return;
    }
    const int g = (bi - XB_) * 256 + threadIdx.x;
    if (g < 18 * 4 * 64) {
        const int s = g >> 8, mt = (g >> 6) & 3, lane = g & 63;
        const int k = s >> 1, cb = (s & 1) * 32;
        const int o  = mt * 16 + (lane & 15);
        const int c0 = cb + (lane >> 4) * 8;
        f16x8 v;
#pragma unroll
        for (int j = 0; j < 8; ++j) v[j] = (_Float16)wgt[o * KSZ + (c0 + j) * 9 + k];
        *(f16x8*)&wpM[(size_t)g * 8] = v;
    } else if (g < 18 * 4 * 64 + 18 * 2 * 64) {
        const int u = g - 18 * 4 * 64;
        const int s = u >> 7, mt = (u >> 6) & 1, lane = u & 63;
        const int k = s >> 1, cb = (s & 1) * 32;
        const int t  = mt * 16 + (lane & 15);
        const int c0 = cb + (lane >> 4) * 8;
        f16x8 v;
#pragma unroll
        for (int j = 0; j < 8; ++j) {
            float w = 0.0f;
            if (t < 18)      w = offw[t * KSZ + (c0 + j) * 9 + k];
            else if (t < 27) w = modw[(t - 18) * KSZ + (c0 + j) * 9 + k];
            v[j] = (_Float16)w;
        }
        *(f16x8*)&wpA[(size_t)u * 8] = v;
    }
}

__device__ __forceinline__ f16x8 splat8(_Float16 h) {
    f16x8 v = {h, h, h, h, h, h, h, h};
    return v;
}

// ---------------------------------------------------------------------------
// Fused main kernel. Block = 256 thr (4 waves) owns a full 128-px row; each
// wave owns 32 px (2 N-tiles). Barrier-free K-loops; the f16 bilinear combine
// runs as pure register-resident packed-f16 vector math (v_pk_fma_f16) and
// produces the MFMA B-fragment in place (n=ln, k=lq*8+j).
// ---------------------------------------------------------------------------
__global__ __launch_bounds__(256, 4) void dcn_main_kernel(
    const _Float16* __restrict__ xT,    // (B, H, W, C) f16
    const _Float16* __restrict__ wpA,   // packed offset/mod weight frags
    const _Float16* __restrict__ wpM,   // packed main weight frags
    const float* __restrict__ offb,     // (18,)
    const float* __restrict__ modb,     // (9,)
    float* __restrict__ out)            // (B, O, H, W)
{
    __shared__ float params[4][27][32];   // [wave][t][px-in-wave-tile]

    const int tid  = threadIdx.x;
    const int lane = tid & 63;
    const int wave = tid >> 6;
    const int lq   = lane >> 4;
    const int ln   = lane & 15;

    const int bi = blockIdx.x;
    const int b  = bi & 7;               // XCD-pinned batch
    const int ho = bi >> 3;

    const _Float16* __restrict__ xbT = xT + (size_t)b * HW_ * 64;

    // ---------------- Phase A: offset/modulator conv via MFMA ----------------
    f32x4 accA[2][2];
#pragma unroll
    for (int mt = 0; mt < 2; ++mt)
#pragma unroll
        for (int nt = 0; nt < 2; ++nt)
            accA[mt][nt] = (f32x4){0.f, 0.f, 0.f, 0.f};

#pragma unroll
    for (int s = 0; s < 18; ++s) {
        const int k = s >> 1, cb = (s & 1) * 32;
        const int ki = k / 3, kj = k - ki * 3;
        const int y  = ho - 1 + ki;
        const bool vy = (y >= 0) && (y < H_);
        f16x8 afA[2];
#pragma unroll
        for (int mt = 0; mt < 2; ++mt)
            afA[mt] = *(const f16x8*)&wpA[(size_t)((s * 2 + mt) * 64 + lane) * 8];
        f16x8 bfA[2];
#pragma unroll
        for (int nt = 0; nt < 2; ++nt) {
            const int wo = wave * 32 + nt * 16 + ln;
            const int xx = wo - 1 + kj;
            const bool v = vy && (xx >= 0) && (xx < W_);
            if (v) {
                bfA[nt] = *(const f16x8*)&xbT[((size_t)(y * W_ + xx)) * 64 + cb + lq * 8];
            } else {
                bfA[nt] = splat8((_Float16)0.0f);
            }
        }
#pragma unroll
        for (int mt = 0; mt < 2; ++mt)
#pragma unroll
            for (int nt = 0; nt < 2; ++nt)
                accA[mt][nt] = __builtin_amdgcn_mfma_f32_16x16x32_f16(afA[mt], bfA[nt], accA[mt][nt], 0, 0, 0);
    }

    // Epilogue A: D col = ln (px in 16-tile), row = mt*16 + lq*4 + r = param t.
#pragma unroll
    for (int mt = 0; mt < 2; ++mt)
#pragma unroll
        for (int nt = 0; nt < 2; ++nt)
#pragma unroll
            for (int r = 0; r < 4; ++r) {
                const int t = mt * 16 + lq * 4 + r;
                const float val = accA[mt][nt][r];
                if (t < 18)      params[wave][t][nt * 16 + ln] = val + offb[t];
                else if (t < 27) params[wave][t][nt * 16 + ln] = 2.0f / (1.0f + expf(-(val + modb[t - 18])));
            }
    __syncthreads();

    // ---------------- Phase B: deformable gather + MFMA ----------------
    f32x4 acc[4][2];
#pragma unroll
    for (int mt = 0; mt < 4; ++mt)
#pragma unroll
        for (int nt = 0; nt < 2; ++nt)
            acc[mt][nt] = (f32x4){0.f, 0.f, 0.f, 0.f};

#pragma unroll
    for (int s = 0; s < 18; ++s) {
        const int k = s >> 1, cb = (s & 1) * 32;
        const int ki = k / 3, kj = k - ki * 3;

        f16x8 af[4];
#pragma unroll
        for (int mt = 0; mt < 4; ++mt)
            af[mt] = *(const f16x8*)&wpM[(size_t)((s * 4 + mt) * 64 + lane) * 8];

        f16x8 bf[2];
#pragma unroll
        for (int nt = 0; nt < 2; ++nt) {
            const int pxw = nt * 16 + ln;
            const int wo  = wave * 32 + pxw;
            const float dy = params[wave][2 * k][pxw];
            const float dx = params[wave][2 * k + 1][pxw];
            const float mk = params[wave][18 + k][pxw];

            const float ys = (float)(ho - 1 + ki) + dy;
            const float xs = (float)(wo - 1 + kj) + dx;
            const float y0f = floorf(ys), x0f = floorf(xs);
            const float wy = ys - y0f, wx = xs - x0f;
            const int y0 = (int)y0f, x0 = (int)x0f;
            const int y1 = y0 + 1,  x1 = x0 + 1;
            const bool vy0 = (y0 >= 0) && (y0 < H_);
            const bool vy1 = (y1 >= 0) && (y1 < H_);
            const bool vx0 = (x0 >= 0) && (x0 < W_);
            const bool vx1 = (x1 >= 0) && (x1 < W_);
            const int yc0 = min(max(y0, 0), H_ - 1);
            const int yc1 = min(max(y1, 0), H_ - 1);
            const int xc0 = min(max(x0, 0), W_ - 1);
            const int xc1 = min(max(x1, 0), W_ - 1);
            float w00 = (1.0f - wy) * (1.0f - wx) * mk; if (!(vy0 && vx0)) w00 = 0.0f;
            float w01 = (1.0f - wy) * wx          * mk; if (!(vy0 && vx1)) w01 = 0.0f;
            float w10 = wy          * (1.0f - wx) * mk; if (!(vy1 && vx0)) w10 = 0.0f;
            float w11 = wy          * wx          * mk; if (!(vy1 && vx1)) w11 = 0.0f;

            const int c0 = cb + lq * 8;
            const f16x8 a00 = *(const f16x8*)&xbT[((size_t)(yc0 * W_ + xc0)) * 64 + c0];
            const f16x8 a01 = *(const f16x8*)&xbT[((size_t)(yc0 * W_ + xc1)) * 64 + c0];
            const f16x8 a10 = *(const f16x8*)&xbT[((size_t)(yc1 * W_ + xc0)) * 64 + c0];
            const f16x8 a11 = *(const f16x8*)&xbT[((size_t)(yc1 * W_ + xc1)) * 64 + c0];

            const f16x8 w00v = splat8((_Float16)w00);
            const f16x8 w01v = splat8((_Float16)w01);
            const f16x8 w10v = splat8((_Float16)w10);
            const f16x8 w11v = splat8((_Float16)w11);

            // pure packed-f16 FMA chain, all in VGPRs
            f16x8 r = a00 * w00v;
            r = a01 * w01v + r;
            r = a10 * w10v + r;
            r = a11 * w11v + r;
            bf[nt] = r;
        }
#pragma unroll
        for (int mt = 0; mt < 4; ++mt)
#pragma unroll
            for (int nt = 0; nt < 2; ++nt)
                acc[mt][nt] = __builtin_amdgcn_mfma_f32_16x16x32_f16(af[mt], bf[nt], acc[mt][nt], 0, 0, 0);
    }

    // Epilogue B: D col = ln -> px, row = o.
    float* __restrict__ ob = out + (size_t)b * O_ * HW_ + (size_t)ho * W_;
#pragma unroll
    for (int mt = 0; mt < 4; ++mt)
#pragma unroll
        for (int nt = 0; nt < 2; ++nt) {
            const int wo = wave * 32 + nt * 16 + ln;
#pragma unroll
            for (int r = 0; r < 4; ++r) {
                const int o = mt * 16 + lq * 4 + r;
                ob[(size_t)o * HW_ + wo] = acc[mt][nt][r];
            }
        }
}

extern "C" void kernel_launch(void* const* d_in, const int* in_sizes, int n_in,
                              void* d_out, int out_size, void* d_ws, size_t ws_size,
                              hipStream_t stream) {
    (void)in_sizes; (void)n_in; (void)out_size; (void)ws_size;
    const float* x    = (const float*)d_in[0];
    const float* offw = (const float*)d_in[1];
    const float* offb = (const float*)d_in[2];
    const float* modw = (const float*)d_in[3];
    const float* modb = (const float*)d_in[4];
    const float* wgt  = (const float*)d_in[5];
    float* out = (float*)d_out;

    _Float16* wpM = (_Float16*)d_ws;                                   // 73728 B
    _Float16* wpA = (_Float16*)((char*)d_ws + WPM_BYTES);              // 36864 B
    _Float16* xT  = (_Float16*)((char*)d_ws + WPM_BYTES + WPA_BYTES);  // 16.78 MB

    prep_kernel<<<XB_ + 27, 256, 0, stream>>>(x, offw, modw, wgt, xT, wpM, wpA);
    dcn_main_kernel<<<B_ * H_, 256, 0, stream>>>(xT, wpA, wpM, offb, modb, out);
}

// Round 8
// 191.139 us; speedup vs baseline: 1.0888x; 1.0792x over previous
//
#include <hip/hip_runtime.h>
#include <math.h>

// Problem constants
#define B_   8
#define C_   64
#define O_   64
#define H_   128
#define W_   128
#define HW_  (H_ * W_)
#define KSZ  576            // C_*9 contraction length

typedef _Float16 f16x8 __attribute__((ext_vector_type(8)));
typedef float    f32x4 __attribute__((ext_vector_type(4)));

#define WPM_BYTES (18 * 4 * 64 * 8 * 2)   // 73728
#define WPA_BYTES (18 * 2 * 64 * 8 * 2)   // 36864
#define TB_       (B_ * HW_ / 64)         // 2048 transpose tiles (64 px x 64 ch)

// ---------------------------------------------------------------------------
// Prep kernel.
// Blocks [0,TB_): LDS-tiled transpose x (B,C,H,W) fp32 -> (B,H,W,C) f16.
//   Read: lanes sweep 64 consecutive px at fixed c (coalesced 256B/wave).
//   LDS tile stride 68 f16 -> bank stride 34 -> 2-way conflicts only (free).
//   Write: each thread stores 32B of consecutive channels; wave covers 2KB
//   contiguous (perfect coalescing).
// Blocks [TB_, TB_+27): prepack weights into f16 MFMA A-fragment layout.
//   A-frag element (chunk s, m-tile mt, lane, j):
//   row = mt*16+(lane&15), k-local = (lane>>4)*8+j; tap k=s>>1, cbase=(s&1)*32.
// ---------------------------------------------------------------------------
__global__ __launch_bounds__(256) void prep_kernel(
    const float* __restrict__ x,
    const float* __restrict__ offw, const float* __restrict__ modw,
    const float* __restrict__ wgt,
    _Float16* __restrict__ xT, _Float16* __restrict__ wpM, _Float16* __restrict__ wpA)
{
    const int bi = blockIdx.x;
    if (bi < TB_) {
        __shared__ _Float16 tile[64 * 68];
        const int tid = threadIdx.x;
        const int b      = bi >> 8;            // 256 tiles per batch
        const int pxbase = (bi & 255) * 64;

        // read: c = (tid>>6)*16 + r, px = tid&63
        const int px = tid & 63;
        const int cr = (tid >> 6) * 16;
        const float* __restrict__ xp = x + (size_t)b * C_ * HW_ + pxbase + px;
#pragma unroll
        for (int r = 0; r < 16; ++r) {
            const int c = cr + r;
            tile[px * 68 + c] = (_Float16)xp[(size_t)c * HW_];
        }
        __syncthreads();

        // write: px2 = tid>>2, c0 = (tid&3)*16
        const int px2 = tid >> 2;
        const int c0  = (tid & 3) * 16;
        f16x8 v0, v1;
#pragma unroll
        for (int j = 0; j < 8; ++j) {
            v0[j] = tile[px2 * 68 + c0 + j];
            v1[j] = tile[px2 * 68 + c0 + 8 + j];
        }
        _Float16* __restrict__ op = xT + ((size_t)b * HW_ + pxbase + px2) * 64 + c0;
        *(f16x8*)&op[0] = v0;
        *(f16x8*)&op[8] = v1;
        return;
    }
    const int g = (bi - TB_) * 256 + threadIdx.x;
    if (g < 18 * 4 * 64) {
        const int s = g >> 8, mt = (g >> 6) & 3, lane = g & 63;
        const int k = s >> 1, cb = (s & 1) * 32;
        const int o  = mt * 16 + (lane & 15);
        const int c0 = cb + (lane >> 4) * 8;
        f16x8 v;
#pragma unroll
        for (int j = 0; j < 8; ++j) v[j] = (_Float16)wgt[o * KSZ + (c0 + j) * 9 + k];
        *(f16x8*)&wpM[(size_t)g * 8] = v;
    } else if (g < 18 * 4 * 64 + 18 * 2 * 64) {
        const int u = g - 18 * 4 * 64;
        const int s = u >> 7, mt = (u >> 6) & 1, lane = u & 63;
        const int k = s >> 1, cb = (s & 1) * 32;
        const int t  = mt * 16 + (lane & 15);
        const int c0 = cb + (lane >> 4) * 8;
        f16x8 v;
#pragma unroll
        for (int j = 0; j < 8; ++j) {
            float w = 0.0f;
            if (t < 18)      w = offw[t * KSZ + (c0 + j) * 9 + k];
            else if (t < 27) w = modw[(t - 18) * KSZ + (c0 + j) * 9 + k];
            v[j] = (_Float16)w;
        }
        *(f16x8*)&wpA[(size_t)u * 8] = v;
    }
}

__device__ __forceinline__ f16x8 splat8(_Float16 h) {
    f16x8 v = {h, h, h, h, h, h, h, h};
    return v;
}

// ---------------------------------------------------------------------------
// Fused main kernel. Block = 256 thr (4 waves) owns a full 128-px row; each
// wave owns 32 px (2 N-tiles). Barrier-free K-loops; packed-f16 bilinear
// combine produces the MFMA B-fragment in place (n=ln, k=lq*8+j).
// NOTE: plain __launch_bounds__(256) — no min-waves clamp. The (256,4) clamp
// capped VGPRs at 128 and caused ~110 MB/dispatch scratch spill (r6/r7).
// ---------------------------------------------------------------------------
__global__ __launch_bounds__(256) void dcn_main_kernel(
    const _Float16* __restrict__ xT,    // (B, H, W, C) f16
    const _Float16* __restrict__ wpA,   // packed offset/mod weight frags
    const _Float16* __restrict__ wpM,   // packed main weight frags
    const float* __restrict__ offb,     // (18,)
    const float* __restrict__ modb,     // (9,)
    float* __restrict__ out)            // (B, O, H, W)
{
    __shared__ float params[4][27][32];   // [wave][t][px-in-wave-tile]

    const int tid  = threadIdx.x;
    const int lane = tid & 63;
    const int wave = tid >> 6;
    const int lq   = lane >> 4;
    const int ln   = lane & 15;

    const int bi = blockIdx.x;
    const int b  = bi & 7;               // XCD-pinned batch
    const int ho = bi >> 3;

    const _Float16* __restrict__ xbT = xT + (size_t)b * HW_ * 64;

    // ---------------- Phase A: offset/modulator conv via MFMA ----------------
    f32x4 accA[2][2];
#pragma unroll
    for (int mt = 0; mt < 2; ++mt)
#pragma unroll
        for (int nt = 0; nt < 2; ++nt)
            accA[mt][nt] = (f32x4){0.f, 0.f, 0.f, 0.f};

#pragma unroll
    for (int s = 0; s < 18; ++s) {
        const int k = s >> 1, cb = (s & 1) * 32;
        const int ki = k / 3, kj = k - ki * 3;
        const int y  = ho - 1 + ki;
        const bool vy = (y >= 0) && (y < H_);
        f16x8 afA[2];
#pragma unroll
        for (int mt = 0; mt < 2; ++mt)
            afA[mt] = *(const f16x8*)&wpA[(size_t)((s * 2 + mt) * 64 + lane) * 8];
        f16x8 bfA[2];
#pragma unroll
        for (int nt = 0; nt < 2; ++nt) {
            const int wo = wave * 32 + nt * 16 + ln;
            const int xx = wo - 1 + kj;
            const bool v = vy && (xx >= 0) && (xx < W_);
            if (v) {
                bfA[nt] = *(const f16x8*)&xbT[((size_t)(y * W_ + xx)) * 64 + cb + lq * 8];
            } else {
                bfA[nt] = splat8((_Float16)0.0f);
            }
        }
#pragma unroll
        for (int mt = 0; mt < 2; ++mt)
#pragma unroll
            for (int nt = 0; nt < 2; ++nt)
                accA[mt][nt] = __builtin_amdgcn_mfma_f32_16x16x32_f16(afA[mt], bfA[nt], accA[mt][nt], 0, 0, 0);
    }

    // Epilogue A: D col = ln (px in 16-tile), row = mt*16 + lq*4 + r = param t.
#pragma unroll
    for (int mt = 0; mt < 2; ++mt)
#pragma unroll
        for (int nt = 0; nt < 2; ++nt)
#pragma unroll
            for (int r = 0; r < 4; ++r) {
                const int t = mt * 16 + lq * 4 + r;
                const float val = accA[mt][nt][r];
                if (t < 18)      params[wave][t][nt * 16 + ln] = val + offb[t];
                else if (t < 27) params[wave][t][nt * 16 + ln] = 2.0f / (1.0f + expf(-(val + modb[t - 18])));
            }
    __syncthreads();

    // ---------------- Phase B: deformable gather + MFMA ----------------
    f32x4 acc[4][2];
#pragma unroll
    for (int mt = 0; mt < 4; ++mt)
#pragma unroll
        for (int nt = 0; nt < 2; ++nt)
            acc[mt][nt] = (f32x4){0.f, 0.f, 0.f, 0.f};

#pragma unroll
    for (int s = 0; s < 18; ++s) {
        const int k = s >> 1, cb = (s & 1) * 32;
        const int ki = k / 3, kj = k - ki * 3;

        f16x8 af[4];
#pragma unroll
        for (int mt = 0; mt < 4; ++mt)
            af[mt] = *(const f16x8*)&wpM[(size_t)((s * 4 + mt) * 64 + lane) * 8];

        f16x8 bf[2];
#pragma unroll
        for (int nt = 0; nt < 2; ++nt) {
            const int pxw = nt * 16 + ln;
            const int wo  = wave * 32 + pxw;
            const float dy = params[wave][2 * k][pxw];
            const float dx = params[wave][2 * k + 1][pxw];
            const float mk = params[wave][18 + k][pxw];

            const float ys = (float)(ho - 1 + ki) + dy;
            const float xs = (float)(wo - 1 + kj) + dx;
            const float y0f = floorf(ys), x0f = floorf(xs);
            const float wy = ys - y0f, wx = xs - x0f;
            const int y0 = (int)y0f, x0 = (int)x0f;
            const int y1 = y0 + 1,  x1 = x0 + 1;
            const bool vy0 = (y0 >= 0) && (y0 < H_);
            const bool vy1 = (y1 >= 0) && (y1 < H_);
            const bool vx0 = (x0 >= 0) && (x0 < W_);
            const bool vx1 = (x1 >= 0) && (x1 < W_);
            const int yc0 = min(max(y0, 0), H_ - 1);
            const int yc1 = min(max(y1, 0), H_ - 1);
            const int xc0 = min(max(x0, 0), W_ - 1);
            const int xc1 = min(max(x1, 0), W_ - 1);
            float w00 = (1.0f - wy) * (1.0f - wx) * mk; if (!(vy0 && vx0)) w00 = 0.0f;
            float w01 = (1.0f - wy) * wx          * mk; if (!(vy0 && vx1)) w01 = 0.0f;
            float w10 = wy          * (1.0f - wx) * mk; if (!(vy1 && vx0)) w10 = 0.0f;
            float w11 = wy          * wx          * mk; if (!(vy1 && vx1)) w11 = 0.0f;

            const int c0 = cb + lq * 8;
            const f16x8 a00 = *(const f16x8*)&xbT[((size_t)(yc0 * W_ + xc0)) * 64 + c0];
            const f16x8 a01 = *(const f16x8*)&xbT[((size_t)(yc0 * W_ + xc1)) * 64 + c0];
            const f16x8 a10 = *(const f16x8*)&xbT[((size_t)(yc1 * W_ + xc0)) * 64 + c0];
            const f16x8 a11 = *(const f16x8*)&xbT[((size_t)(yc1 * W_ + xc1)) * 64 + c0];

            const f16x8 w00v = splat8((_Float16)w00);
            const f16x8 w01v = splat8((_Float16)w01);
            const f16x8 w10v = splat8((_Float16)w10);
            const f16x8 w11v = splat8((_Float16)w11);

            f16x8 r = a00 * w00v;
            r = a01 * w01v + r;
            r = a10 * w10v + r;
            r = a11 * w11v + r;
            bf[nt] = r;
        }
#pragma unroll
        for (int mt = 0; mt < 4; ++mt)
#pragma unroll
            for (int nt = 0; nt < 2; ++nt)
                acc[mt][nt] = __builtin_amdgcn_mfma_f32_16x16x32_f16(af[mt], bf[nt], acc[mt][nt], 0, 0, 0);
    }

    // Epilogue B: D col = ln -> px, row = o.
    float* __restrict__ ob = out + (size_t)b * O_ * HW_ + (size_t)ho * W_;
#pragma unroll
    for (int mt = 0; mt < 4; ++mt)
#pragma unroll
        for (int nt = 0; nt < 2; ++nt) {
            const int wo = wave * 32 + nt * 16 + ln;
#pragma unroll
            for (int r = 0; r < 4; ++r) {
                const int o = mt * 16 + lq * 4 + r;
                ob[(size_t)o * HW_ + wo] = acc[mt][nt][r];
            }
        }
}

extern "C" void kernel_launch(void* const* d_in, const int* in_sizes, int n_in,
                              void* d_out, int out_size, void* d_ws, size_t ws_size,
                              hipStream_t stream) {
    (void)in_sizes; (void)n_in; (void)out_size; (void)ws_size;
    const float* x    = (const float*)d_in[0];
    const float* offw = (const float*)d_in[1];
    const float* offb = (const float*)d_in[2];
    const float* modw = (const float*)d_in[3];
    const float* modb = (const float*)d_in[4];
    const float* wgt  = (const float*)d_in[5];
    float* out = (float*)d_out;

    _Float16* wpM = (_Float16*)d_ws;                                   // 73728 B
    _Float16* wpA = (_Float16*)((char*)d_ws + WPM_BYTES);              // 36864 B
    _Float16* xT  = (_Float16*)((char*)d_ws + WPM_BYTES + WPA_BYTES);  // 16.78 MB

    prep_kernel<<<TB_ + 27, 256, 0, stream>>>(x, offw, modw, wgt, xT, wpM, wpA);
    dcn_main_kernel<<<B_ * H_, 256, 0, stream>>>(xT, wpA, wpM, offb, modb, out);
}